// Round 1
// baseline (3117.521 us; speedup 1.0000x reference)
//
#include <hip/hip_runtime.h>
#include <hip/hip_bf16.h>
#include <math.h>

#define NB 256
#define NN 400
#define NH 128
#define NCOUT 16

static constexpr float LOGIT_THRESH = 0.40546510810816444f; // ln(1.5) : sigmoid(z)>0.6 <=> z>ln1.5
static constexpr float LN_EPS = 1e-5f;

// ---------------- Kernel 1: mask[b,s,d] = (adj@W_adj + b_adj > ln1.5) | (s==d) ----------------
// 64x64 C-tile, BK=16, 256 threads, 4x4 micro-tile (rows ty+16i, cols 4tx+j)
__global__ __launch_bounds__(256) void k_mask(const float* __restrict__ adj,
                                              const float* __restrict__ Wadj,
                                              const float* __restrict__ badj,
                                              unsigned char* __restrict__ mask)
{
    const int b  = blockIdx.z;
    const int s0 = blockIdx.y * 64;
    const int d0 = blockIdx.x * 64;
    const int t  = threadIdx.x;
    const int tx = t & 15, ty = t >> 4;

    __shared__ float as[64][16];
    __shared__ float bs[16][64];

    float acc[4][4] = {};

    const int lkk = t & 15;       // A-load: k within tile
    const int lr0 = t >> 4;       // A-load: row base (16 rows/pass)
    const int ldd = t & 63;       // B-load: col
    const int lkb = t >> 6;       // B-load: k base (4 k/pass)

    const float* adjb = adj + (long)b * NN * NN;

    for (int k0 = 0; k0 < NN; k0 += 16) {   // 400 = 25*16 exactly
#pragma unroll
        for (int p = 0; p < 4; ++p) {
            int row = lr0 + p * 16;
            int s = s0 + row;
            as[row][lkk] = (s < NN) ? adjb[(long)s * NN + k0 + lkk] : 0.f;
        }
#pragma unroll
        for (int p = 0; p < 4; ++p) {
            int kk = lkb + p * 4;
            int d = d0 + ldd;
            bs[kk][ldd] = (d < NN) ? Wadj[(k0 + kk) * NN + d] : 0.f;
        }
        __syncthreads();
#pragma unroll
        for (int k = 0; k < 16; ++k) {
            float a_[4];
            a_[0] = as[ty][k];      a_[1] = as[ty + 16][k];
            a_[2] = as[ty + 32][k]; a_[3] = as[ty + 48][k];
            float4 bv = *(const float4*)&bs[k][tx * 4];
#pragma unroll
            for (int i = 0; i < 4; ++i) {
                acc[i][0] += a_[i] * bv.x; acc[i][1] += a_[i] * bv.y;
                acc[i][2] += a_[i] * bv.z; acc[i][3] += a_[i] * bv.w;
            }
        }
        __syncthreads();
    }

    unsigned char* mb = mask + (long)b * NN * NN;
#pragma unroll
    for (int i = 0; i < 4; ++i) {
        int s = s0 + ty + 16 * i;
        if (s >= NN) continue;
#pragma unroll
        for (int j = 0; j < 4; ++j) {
            int d = d0 + tx * 4 + j;
            if (d >= NN) continue;
            float c = acc[i][j] + badj[d];
            mb[(long)s * NN + d] = (c > LOGIT_THRESH || s == d) ? 1 : 0;
        }
    }
}

// ---------------- Kernel 2: hp = h @ W  (per-batch 400x128 @ 128x128) ----------------
// 64-row x 128-col tile, BK=16, 256 threads, 8x4 micro-tile (rows ty+8i, cols 4tx+j)
__global__ __launch_bounds__(256) void k_hp(const float* __restrict__ hin,
                                            const float* __restrict__ W,
                                            float* __restrict__ hp)
{
    const int b  = blockIdx.y;
    const int r0 = blockIdx.x * 64;
    const int t  = threadIdx.x;
    const int tx = t & 31, ty = t >> 5;  // ty 0..7

    __shared__ float as[64][16];
    __shared__ float ws[16][128];

    float acc[8][4] = {};

    const int lkk = t & 15, lr0 = t >> 4;
    const int lc  = t & 127, lkb = t >> 7; // 0..1

    const float* hb = hin + (long)b * NN * NH;

    for (int k0 = 0; k0 < NH; k0 += 16) {  // 128 = 8*16 exactly
#pragma unroll
        for (int p = 0; p < 4; ++p) {
            int row = lr0 + p * 16;
            int r = r0 + row;
            as[row][lkk] = (r < NN) ? hb[(long)r * NH + k0 + lkk] : 0.f;
        }
#pragma unroll
        for (int p = 0; p < 8; ++p) {
            int kk = lkb + p * 2;
            ws[kk][lc] = W[(k0 + kk) * NH + lc];
        }
        __syncthreads();
#pragma unroll
        for (int k = 0; k < 16; ++k) {
            float4 bv = *(const float4*)&ws[k][tx * 4];
#pragma unroll
            for (int i = 0; i < 8; ++i) {
                float a = as[ty + 8 * i][k];
                acc[i][0] += a * bv.x; acc[i][1] += a * bv.y;
                acc[i][2] += a * bv.z; acc[i][3] += a * bv.w;
            }
        }
        __syncthreads();
    }

    float* hpb = hp + (long)b * NN * NH;
#pragma unroll
    for (int i = 0; i < 8; ++i) {
        int r = r0 + ty + 8 * i;
        if (r >= NN) continue;
        float4 o = make_float4(acc[i][0], acc[i][1], acc[i][2], acc[i][3]);
        *(float4*)&hpb[(long)r * NH + tx * 4] = o;
    }
}

// ---------------- Kernel 2b: e_src/e_dst = hp . a_src / a_dst per row ----------------
__global__ __launch_bounds__(128) void k_e(const float* __restrict__ hp,
                                           const float* __restrict__ asrc,
                                           const float* __restrict__ adst,
                                           float* __restrict__ esrc,
                                           float* __restrict__ edst)
{
    const long row = blockIdx.x;           // 0 .. B*N-1
    const int t = threadIdx.x;
    float v = hp[row * NH + t];
    __shared__ float rs[128], rd[128];
    rs[t] = v * asrc[t];
    rd[t] = v * adst[t];
    __syncthreads();
    for (int off = 64; off > 0; off >>= 1) {
        if (t < off) { rs[t] += rs[t + off]; rd[t] += rd[t + off]; }
        __syncthreads();
    }
    if (t == 0) { esrc[row] = rs[0]; edst[row] = rd[0]; }
}

// ---------------- Kernel 3a: per-dst masked softmax stats (max, denom) ----------------
__global__ __launch_bounds__(128) void k_softstats(const unsigned char* __restrict__ mask,
                                                   const float* __restrict__ esrc,
                                                   const float* __restrict__ edst,
                                                   float* __restrict__ mrow,
                                                   float* __restrict__ dens)
{
    const int b = blockIdx.y;
    const int d = blockIdx.x * 128 + threadIdx.x;
    if (d >= NN) return;
    const float ed = edst[b * NN + d];
    const unsigned char* mb = mask + (long)b * NN * NN + d;
    const float* es = esrc + b * NN;
    float m = -INFINITY;
    for (int s = 0; s < NN; ++s) {
        if (mb[(long)s * NN]) {
            float sc = es[s] + ed;
            sc = sc > 0.f ? sc : 0.2f * sc;
            m = fmaxf(m, sc);
        }
    }
    float den = 0.f;
    for (int s = 0; s < NN; ++s) {
        if (mb[(long)s * NN]) {
            float sc = es[s] + ed;
            sc = sc > 0.f ? sc : 0.2f * sc;
            den += __expf(sc - m);
        }
    }
    mrow[b * NN + d] = m;
    dens[b * NN + d] = den;
}

// ---------------- Kernel 3b: h_out[b,d,:] = (sum_s P[s,d]*hp[s,:]) / den[d] + bias ----------------
// 64 dst x 128 feat per block; 128 threads: tx=t&31 -> cols 4tx..+3, ty=t>>5 -> dst 16ty..+15
__global__ __launch_bounds__(128) void k_aggr(const unsigned char* __restrict__ mask,
                                              const float* __restrict__ hp,
                                              const float* __restrict__ esrc,
                                              const float* __restrict__ edst,
                                              const float* __restrict__ mrow,
                                              const float* __restrict__ dens,
                                              const float* __restrict__ bias,
                                              float* __restrict__ hout)
{
    const int b  = blockIdx.y;
    const int d0 = blockIdx.x * 64;
    const int t  = threadIdx.x;
    const int tx = t & 31, ty = t >> 5;   // ty 0..3

    __shared__ float pl[2][64];
    __shared__ float edl[64], ml[64], idl[64];

    if (t < 64) {
        int d = d0 + t;
        bool v = d < NN;
        edl[t] = v ? edst[b * NN + d] : 0.f;
        ml[t]  = v ? mrow[b * NN + d] : 0.f;
        idl[t] = v ? 1.f / dens[b * NN + d] : 0.f;
    }
    __syncthreads();

    float4 acc[16];
#pragma unroll
    for (int i = 0; i < 16; ++i) acc[i] = make_float4(0.f, 0.f, 0.f, 0.f);

    const float* hpb = hp + (long)b * NN * NH;
    const unsigned char* mb = mask + (long)b * NN * NN;
    const float* es = esrc + b * NN;

    const int sj = t & 63;
    const int sh = t >> 6;  // 0/1: which of the two source rows this thread scores

    for (int s = 0; s < NN; s += 2) {      // 400 even
        {
            int ss = s + sh;
            float sc = es[ss] + edl[sj];
            sc = sc > 0.f ? sc : 0.2f * sc;
            unsigned char mk = (d0 + sj < NN) ? mb[(long)ss * NN + d0 + sj] : (unsigned char)0;
            pl[sh][sj] = mk ? __expf(sc - ml[sj]) : 0.f;
        }
        __syncthreads();
        float4 h0 = *(const float4*)&hpb[(long)s * NH + tx * 4];
        float4 h1 = *(const float4*)&hpb[(long)(s + 1) * NH + tx * 4];
#pragma unroll
        for (int jv = 0; jv < 4; ++jv) {
            float4 p0 = *(const float4*)&pl[0][ty * 16 + jv * 4];
            float4 p1 = *(const float4*)&pl[1][ty * 16 + jv * 4];
            float p0a[4] = {p0.x, p0.y, p0.z, p0.w};
            float p1a[4] = {p1.x, p1.y, p1.z, p1.w};
#pragma unroll
            for (int c = 0; c < 4; ++c) {
                const int jj = jv * 4 + c;
                acc[jj].x += p0a[c] * h0.x + p1a[c] * h1.x;
                acc[jj].y += p0a[c] * h0.y + p1a[c] * h1.y;
                acc[jj].z += p0a[c] * h0.z + p1a[c] * h1.z;
                acc[jj].w += p0a[c] * h0.w + p1a[c] * h1.w;
            }
        }
        __syncthreads();
    }

    const float4 bv = *(const float4*)&bias[tx * 4];
    float* hb = hout + (long)b * NN * NH;
#pragma unroll
    for (int jj = 0; jj < 16; ++jj) {
        int j = ty * 16 + jj;
        int d = d0 + j;
        if (d >= NN) continue;
        float id = idl[j];
        float4 o;
        o.x = acc[jj].x * id + bv.x;
        o.y = acc[jj].y * id + bv.y;
        o.z = acc[jj].z * id + bv.z;
        o.w = acc[jj].w * id + bv.w;
        *(float4*)&hb[(long)d * NH + tx * 4] = o;
    }
}

// ---------------- Kernel 4: in-place LayerNorm(H) + ReLU ----------------
__global__ __launch_bounds__(128) void k_ln_relu(float* __restrict__ h,
                                                 const float* __restrict__ g,
                                                 const float* __restrict__ bb)
{
    const long row = blockIdx.x;
    const int t = threadIdx.x;
    float x = h[row * NH + t];
    __shared__ float red[128];
    red[t] = x;
    __syncthreads();
    for (int off = 64; off > 0; off >>= 1) { if (t < off) red[t] += red[t + off]; __syncthreads(); }
    float mean = red[0] * (1.f / NH);
    __syncthreads();
    float xm = x - mean;
    red[t] = xm * xm;
    __syncthreads();
    for (int off = 64; off > 0; off >>= 1) { if (t < off) red[t] += red[t + off]; __syncthreads(); }
    float var = red[0] * (1.f / NH);
    float y = xm * rsqrtf(var + LN_EPS) * g[t] + bb[t];
    h[row * NH + t] = fmaxf(y, 0.f);
}

// ---------------- Kernel 5: mean-pool over N + final linear ----------------
__global__ __launch_bounds__(128) void k_pool_lin(const float* __restrict__ h,
                                                  const float* __restrict__ Wl,
                                                  const float* __restrict__ bl,
                                                  float* __restrict__ out)
{
    const int b = blockIdx.x;
    const int t = threadIdx.x;
    const float* hb = h + (long)b * NN * NH;
    float s = 0.f;
    for (int n = 0; n < NN; ++n) s += hb[(long)n * NH + t];
    __shared__ float gl[128];
    gl[t] = s * (1.f / NN);
    __syncthreads();
    if (t < NCOUT) {
        float o = bl[t];
        for (int k = 0; k < NH; ++k) o += gl[k] * Wl[k * NCOUT + t];
        out[b * NCOUT + t] = o;
    }
}

extern "C" void kernel_launch(void* const* d_in, const int* in_sizes, int n_in,
                              void* d_out, int out_size, void* d_ws, size_t ws_size,
                              hipStream_t stream)
{
    const float* x    = (const float*)d_in[0];
    const float* adj  = (const float*)d_in[1];
    const float* Wadj = (const float*)d_in[4];
    const float* badj = (const float*)d_in[5];
    const float* W1   = (const float*)d_in[6];
    const float* as1  = (const float*)d_in[7];
    const float* ad1  = (const float*)d_in[8];
    const float* b1   = (const float*)d_in[9];
    const float* W2   = (const float*)d_in[10];
    const float* as2  = (const float*)d_in[11];
    const float* ad2  = (const float*)d_in[12];
    const float* b2   = (const float*)d_in[13];
    const float* lng  = (const float*)d_in[14];
    const float* lnb  = (const float*)d_in[15];
    const float* Wlin = (const float*)d_in[16];
    const float* blin = (const float*)d_in[17];
    float* out = (float*)d_out;

    // workspace layout (bytes):
    //   mask  : 0           .. 40,960,000   (B*N*N uint8)
    //   hp    : 40,960,000  .. 93,388,800   (B*N*H f32)
    //   hbuf  : 93,388,800  .. 145,817,600  (B*N*H f32)
    //   esrc/edst/mrow/dens : 4 x 409,600 f32
    char* ws = (char*)d_ws;
    unsigned char* mask = (unsigned char*)ws;
    float* hp   = (float*)(ws + 40960000);
    float* hbuf = (float*)(ws + 40960000 + 52428800);
    float* esrc = (float*)(ws + 145817600);
    float* edst = (float*)(ws + 146227200);
    float* mrow = (float*)(ws + 146636800);
    float* dens = (float*)(ws + 147046400);

    // mask
    hipLaunchKernelGGL(k_mask, dim3(7, 7, NB), dim3(256), 0, stream, adj, Wadj, badj, mask);

    // ---- GAT layer 1 (W1) ----
    hipLaunchKernelGGL(k_hp,        dim3(7, NB),     dim3(256), 0, stream, x, W1, hp);
    hipLaunchKernelGGL(k_e,         dim3(NB * NN),   dim3(128), 0, stream, hp, as1, ad1, esrc, edst);
    hipLaunchKernelGGL(k_softstats, dim3(4, NB),     dim3(128), 0, stream, mask, esrc, edst, mrow, dens);
    hipLaunchKernelGGL(k_aggr,      dim3(7, NB),     dim3(128), 0, stream, mask, hp, esrc, edst, mrow, dens, b1, hbuf);
    hipLaunchKernelGGL(k_ln_relu,   dim3(NB * NN),   dim3(128), 0, stream, hbuf, lng, lnb);

    // ---- GAT layer 2 (W2) ----
    hipLaunchKernelGGL(k_hp,        dim3(7, NB),     dim3(256), 0, stream, hbuf, W2, hp);
    hipLaunchKernelGGL(k_e,         dim3(NB * NN),   dim3(128), 0, stream, hp, as2, ad2, esrc, edst);
    hipLaunchKernelGGL(k_softstats, dim3(4, NB),     dim3(128), 0, stream, mask, esrc, edst, mrow, dens);
    hipLaunchKernelGGL(k_aggr,      dim3(7, NB),     dim3(128), 0, stream, mask, hp, esrc, edst, mrow, dens, b2, hbuf);
    hipLaunchKernelGGL(k_ln_relu,   dim3(NB * NN),   dim3(128), 0, stream, hbuf, lng, lnb);

    // ---- GAT layer 3 (W2 again, no LN/ReLU) ----
    hipLaunchKernelGGL(k_hp,        dim3(7, NB),     dim3(256), 0, stream, hbuf, W2, hp);
    hipLaunchKernelGGL(k_e,         dim3(NB * NN),   dim3(128), 0, stream, hp, as2, ad2, esrc, edst);
    hipLaunchKernelGGL(k_softstats, dim3(4, NB),     dim3(128), 0, stream, mask, esrc, edst, mrow, dens);
    hipLaunchKernelGGL(k_aggr,      dim3(7, NB),     dim3(128), 0, stream, mask, hp, esrc, edst, mrow, dens, b2, hbuf);

    // pool + linear
    hipLaunchKernelGGL(k_pool_lin,  dim3(NB),        dim3(128), 0, stream, hbuf, Wlin, blin, out);
}

// Round 2
// 1698.451 us; speedup vs baseline: 1.8355x; 1.8355x over previous
//
#include <hip/hip_runtime.h>
#include <hip/hip_bf16.h>
#include <math.h>

#define NB 256
#define NN 400
#define NH 128
#define NCOUT 16
#define KP 416   // padded K for Wt (13*32)

static constexpr float LOGIT_THRESH = 0.40546510810816444f; // ln(1.5)
static constexpr float LN_EPS = 1e-5f;

typedef __attribute__((ext_vector_type(8))) short short8v;
typedef __attribute__((ext_vector_type(4))) float f32x4;

static __device__ __forceinline__ short f2bf_rne(float f) {
    unsigned u = __float_as_uint(f);
    unsigned r = (u + 0x7fff + ((u >> 16) & 1)) >> 16;
    return (short)r;
}
static __device__ __forceinline__ float bf2f(short s) {
    return __uint_as_float(((unsigned)(unsigned short)s) << 16);
}

// swizzled LDS offset (in shorts) for 16B chunk c (0..3) of row r in a [R][32]-bf16 tile
static __device__ __forceinline__ int soff(int r, int c) {
    return r * 32 + ((c ^ ((r >> 1) & 3)) << 3);
}

// ---------------- Kernel 0: W_adj -> bf16 hi/lo, transposed + padded: Wt[512][416] ----------------
__global__ __launch_bounds__(256) void k_wprep(const float* __restrict__ W,
                                               short* __restrict__ WtH,
                                               short* __restrict__ WtL)
{
    const int k0 = blockIdx.x * 32, d0 = blockIdx.y * 32;
    __shared__ float tile[32][33];
    const int t = threadIdx.x, cc = t & 31, rr = t >> 5;   // rr 0..7
#pragma unroll
    for (int i = 0; i < 4; ++i) {
        int k = k0 + rr + i * 8, d = d0 + cc;
        tile[rr + i * 8][cc] = (k < NN && d < NN) ? W[k * NN + d] : 0.f;
    }
    __syncthreads();
#pragma unroll
    for (int i = 0; i < 4; ++i) {
        int dr = rr + i * 8;
        int d = d0 + dr, k = k0 + cc;
        float v = tile[cc][dr];
        short h = f2bf_rne(v);
        WtH[d * KP + k] = h;
        WtL[d * KP + k] = f2bf_rne(v - bf2f(h));
    }
}

// ---------------- Kernel 1: mask = (adj@W_adj + b_adj > ln1.5) | (s==d), bf16-split MFMA ----------------
// 128x128 tile, 256 threads = 4 waves (2x2 of 64x64), K padded to 416
__global__ __launch_bounds__(256) void k_mask(const float* __restrict__ adj,
                                              const short* __restrict__ WtH,
                                              const short* __restrict__ WtL,
                                              const float* __restrict__ badj,
                                              unsigned char* __restrict__ mask)
{
    const int b  = blockIdx.z;
    const int s0 = blockIdx.y * 128;
    const int d0 = blockIdx.x * 128;
    const int t  = threadIdx.x;
    const int lane = t & 63, w = t >> 6;
    const int wm = w >> 1, wn = w & 1;

    __shared__ short Ah[128 * 32], Al[128 * 32], Bh[128 * 32], Bl[128 * 32];

    f32x4 acc[4][4];
#pragma unroll
    for (int i = 0; i < 4; ++i)
#pragma unroll
        for (int j = 0; j < 4; ++j) acc[i][j] = (f32x4){0.f, 0.f, 0.f, 0.f};

    // staging mapping: r = (t>>2) (+64i), c = t&3
    const int sr = t >> 2, sc_ = t & 3;
    // fragment-read offsets
    const int fc = lane >> 4;
    int aoff[4], boff[4];
#pragma unroll
    for (int i = 0; i < 4; ++i) {
        aoff[i] = soff(wm * 64 + i * 16 + (lane & 15), fc);
        boff[i] = soff(wn * 64 + i * 16 + (lane & 15), fc);
    }

    const float* adjb = adj + (long)b * NN * NN;

    for (int kt = 0; kt < 13; ++kt) {
        const int k0 = kt * 32;
        __syncthreads();   // protect LDS from prior-iter readers
#pragma unroll
        for (int i = 0; i < 2; ++i) {
            const int rr = sr + 64 * i;
            // ---- A: adj rows (f32 -> hi/lo bf16) ----
            {
                const int s = s0 + rr, kg = k0 + sc_ * 8;
                float x[8];
                if (s < NN && kg < NN) {
                    float4 u0 = *(const float4*)&adjb[(long)s * NN + kg];
                    float4 u1 = *(const float4*)&adjb[(long)s * NN + kg + 4];
                    x[0]=u0.x; x[1]=u0.y; x[2]=u0.z; x[3]=u0.w;
                    x[4]=u1.x; x[5]=u1.y; x[6]=u1.z; x[7]=u1.w;
                } else {
#pragma unroll
                    for (int j = 0; j < 8; ++j) x[j] = 0.f;
                }
                short8v hv, lv;
#pragma unroll
                for (int j = 0; j < 8; ++j) {
                    short h = f2bf_rne(x[j]);
                    hv[j] = h;
                    lv[j] = f2bf_rne(x[j] - bf2f(h));
                }
                *(short8v*)&Ah[soff(rr, sc_)] = hv;
                *(short8v*)&Al[soff(rr, sc_)] = lv;
            }
            // ---- B: pre-converted Wt rows ----
            {
                const long gi = (long)(d0 + rr) * KP + k0 + sc_ * 8;
                *(short8v*)&Bh[soff(rr, sc_)] = *(const short8v*)&WtH[gi];
                *(short8v*)&Bl[soff(rr, sc_)] = *(const short8v*)&WtL[gi];
            }
        }
        __syncthreads();

        short8v ah[4], al[4], bh[4], bl[4];
#pragma unroll
        for (int i = 0; i < 4; ++i) {
            ah[i] = *(const short8v*)&Ah[aoff[i]];
            al[i] = *(const short8v*)&Al[aoff[i]];
            bh[i] = *(const short8v*)&Bh[boff[i]];
            bl[i] = *(const short8v*)&Bl[boff[i]];
        }
#pragma unroll
        for (int mi = 0; mi < 4; ++mi)
#pragma unroll
            for (int ni = 0; ni < 4; ++ni) {
                acc[mi][ni] = __builtin_amdgcn_mfma_f32_16x16x32_bf16(ah[mi], bh[ni], acc[mi][ni], 0, 0, 0);
                acc[mi][ni] = __builtin_amdgcn_mfma_f32_16x16x32_bf16(al[mi], bh[ni], acc[mi][ni], 0, 0, 0);
                acc[mi][ni] = __builtin_amdgcn_mfma_f32_16x16x32_bf16(ah[mi], bl[ni], acc[mi][ni], 0, 0, 0);
            }
    }

    // epilogue: C layout col = lane&15, row = (lane>>4)*4 + reg
    unsigned char* mb = mask + (long)b * NN * NN;
    const int colb = d0 + wn * 64 + (lane & 15);
    const int rowb = s0 + wm * 64 + ((lane >> 4) << 2);
#pragma unroll
    for (int ni = 0; ni < 4; ++ni) {
        const int d = colb + ni * 16;
        if (d >= NN) continue;
        const float bv = badj[d];
#pragma unroll
        for (int mi = 0; mi < 4; ++mi) {
#pragma unroll
            for (int j = 0; j < 4; ++j) {
                const int s = rowb + mi * 16 + j;
                if (s < NN)
                    mb[(long)s * NN + d] = ((acc[mi][ni][j] + bv) > LOGIT_THRESH || s == d) ? 1 : 0;
            }
        }
    }
}

// ---------------- Kernel 2: hp = h @ W  (per-batch 400x128 @ 128x128, fp32) ----------------
__global__ __launch_bounds__(256) void k_hp(const float* __restrict__ hin,
                                            const float* __restrict__ W,
                                            float* __restrict__ hp)
{
    const int b  = blockIdx.y;
    const int r0 = blockIdx.x * 64;
    const int t  = threadIdx.x;
    const int tx = t & 31, ty = t >> 5;

    __shared__ float as[64][16];
    __shared__ float ws[16][128];

    float acc[8][4] = {};

    const int lkk = t & 15, lr0 = t >> 4;
    const int lc  = t & 127, lkb = t >> 7;

    const float* hb = hin + (long)b * NN * NH;

    for (int k0 = 0; k0 < NH; k0 += 16) {
#pragma unroll
        for (int p = 0; p < 4; ++p) {
            int row = lr0 + p * 16;
            int r = r0 + row;
            as[row][lkk] = (r < NN) ? hb[(long)r * NH + k0 + lkk] : 0.f;
        }
#pragma unroll
        for (int p = 0; p < 8; ++p) {
            int kk = lkb + p * 2;
            ws[kk][lc] = W[(k0 + kk) * NH + lc];
        }
        __syncthreads();
#pragma unroll
        for (int k = 0; k < 16; ++k) {
            float4 bv = *(const float4*)&ws[k][tx * 4];
#pragma unroll
            for (int i = 0; i < 8; ++i) {
                float a = as[ty + 8 * i][k];
                acc[i][0] += a * bv.x; acc[i][1] += a * bv.y;
                acc[i][2] += a * bv.z; acc[i][3] += a * bv.w;
            }
        }
        __syncthreads();
    }

    float* hpb = hp + (long)b * NN * NH;
#pragma unroll
    for (int i = 0; i < 8; ++i) {
        int r = r0 + ty + 8 * i;
        if (r >= NN) continue;
        *(float4*)&hpb[(long)r * NH + tx * 4] =
            make_float4(acc[i][0], acc[i][1], acc[i][2], acc[i][3]);
    }
}

// ---------------- Kernel 2b: e_src/e_dst per row, wave-per-row ----------------
__global__ __launch_bounds__(256) void k_e(const float* __restrict__ hp,
                                           const float* __restrict__ asrc,
                                           const float* __restrict__ adst,
                                           float* __restrict__ esrc,
                                           float* __restrict__ edst)
{
    const int lane = threadIdx.x & 63, wid = threadIdx.x >> 6;
    const long row = (long)blockIdx.x * 4 + wid;
    float v0 = hp[row * NH + lane], v1 = hp[row * NH + 64 + lane];
    float s = v0 * asrc[lane] + v1 * asrc[64 + lane];
    float d = v0 * adst[lane] + v1 * adst[64 + lane];
#pragma unroll
    for (int off = 32; off > 0; off >>= 1) {
        s += __shfl_xor(s, off);
        d += __shfl_xor(d, off);
    }
    if (lane == 0) { esrc[row] = s; edst[row] = d; }
}

// ---------------- Kernel 3: fused attention aggregation (one-pass softmax, no max-sub) ----------------
// h_out[b,d,:] = (sum_s p[s,d]*hp[s,:]) / (sum_s p[s,d]) + bias,  p = mask ? exp(leaky(score)) : 0
__global__ __launch_bounds__(128) void k_aggr(const unsigned char* __restrict__ mask,
                                              const float* __restrict__ hp,
                                              const float* __restrict__ esrc,
                                              const float* __restrict__ edst,
                                              const float* __restrict__ bias,
                                              float* __restrict__ hout)
{
    const int b  = blockIdx.y;
    const int d0 = blockIdx.x * 64;
    const int t  = threadIdx.x;
    const int tx = t & 31, ty = t >> 5;

    __shared__ float pl[2][64];
    __shared__ float edl[64];
    __shared__ float den2[2][64];

    if (t < 64) {
        int d = d0 + t;
        edl[t] = (d < NN) ? edst[b * NN + d] : 0.f;
    }
    __syncthreads();

    f32x4 acc[16];
#pragma unroll
    for (int i = 0; i < 16; ++i) acc[i] = (f32x4){0.f, 0.f, 0.f, 0.f};

    const float* hpb = hp + (long)b * NN * NH;
    const unsigned char* mb = mask + (long)b * NN * NN;
    const float* es = esrc + b * NN;

    const int sj = t & 63;
    const int sh = t >> 6;
    float denloc = 0.f;

    for (int s = 0; s < NN; s += 2) {
        {
            int ss = s + sh;
            float sc = es[ss] + edl[sj];
            sc = sc > 0.f ? sc : 0.2f * sc;
            unsigned char mk = (d0 + sj < NN) ? mb[(long)ss * NN + d0 + sj] : (unsigned char)0;
            float p = mk ? __expf(sc) : 0.f;
            pl[sh][sj] = p;
            denloc += p;
        }
        __syncthreads();
        float4 h0 = *(const float4*)&hpb[(long)s * NH + tx * 4];
        float4 h1 = *(const float4*)&hpb[(long)(s + 1) * NH + tx * 4];
#pragma unroll
        for (int jv = 0; jv < 4; ++jv) {
            float4 p0 = *(const float4*)&pl[0][ty * 16 + jv * 4];
            float4 p1 = *(const float4*)&pl[1][ty * 16 + jv * 4];
            float p0a[4] = {p0.x, p0.y, p0.z, p0.w};
            float p1a[4] = {p1.x, p1.y, p1.z, p1.w};
#pragma unroll
            for (int c = 0; c < 4; ++c) {
                const int jj = jv * 4 + c;
                acc[jj].x += p0a[c] * h0.x + p1a[c] * h1.x;
                acc[jj].y += p0a[c] * h0.y + p1a[c] * h1.y;
                acc[jj].z += p0a[c] * h0.z + p1a[c] * h1.z;
                acc[jj].w += p0a[c] * h0.w + p1a[c] * h1.w;
            }
        }
        __syncthreads();
    }

    den2[sh][sj] = denloc;
    __syncthreads();

    const float4 bv = *(const float4*)&bias[tx * 4];
    float* hb = hout + (long)b * NN * NH;
#pragma unroll
    for (int jj = 0; jj < 16; ++jj) {
        int j = ty * 16 + jj;
        int d = d0 + j;
        if (d >= NN) continue;
        float id = 1.f / (den2[0][j] + den2[1][j]);
        float4 o;
        o.x = acc[jj].x * id + bv.x;
        o.y = acc[jj].y * id + bv.y;
        o.z = acc[jj].z * id + bv.z;
        o.w = acc[jj].w * id + bv.w;
        *(float4*)&hb[(long)d * NH + tx * 4] = o;
    }
}

// ---------------- Kernel 4: in-place LayerNorm(H) + ReLU ----------------
__global__ __launch_bounds__(128) void k_ln_relu(float* __restrict__ h,
                                                 const float* __restrict__ g,
                                                 const float* __restrict__ bb)
{
    const long row = blockIdx.x;
    const int t = threadIdx.x;
    float x = h[row * NH + t];
    __shared__ float red[128];
    red[t] = x;
    __syncthreads();
    for (int off = 64; off > 0; off >>= 1) { if (t < off) red[t] += red[t + off]; __syncthreads(); }
    float mean = red[0] * (1.f / NH);
    __syncthreads();
    float xm = x - mean;
    red[t] = xm * xm;
    __syncthreads();
    for (int off = 64; off > 0; off >>= 1) { if (t < off) red[t] += red[t + off]; __syncthreads(); }
    float var = red[0] * (1.f / NH);
    float y = xm * rsqrtf(var + LN_EPS) * g[t] + bb[t];
    h[row * NH + t] = fmaxf(y, 0.f);
}

// ---------------- Kernel 5: mean-pool over N + final linear ----------------
__global__ __launch_bounds__(128) void k_pool_lin(const float* __restrict__ h,
                                                  const float* __restrict__ Wl,
                                                  const float* __restrict__ bl,
                                                  float* __restrict__ out)
{
    const int b = blockIdx.x;
    const int t = threadIdx.x;
    const float* hb = h + (long)b * NN * NH;
    float s = 0.f;
    for (int n = 0; n < NN; ++n) s += hb[(long)n * NH + t];
    __shared__ float gl[128];
    gl[t] = s * (1.f / NN);
    __syncthreads();
    if (t < NCOUT) {
        float o = bl[t];
        for (int k = 0; k < NH; ++k) o += gl[k] * Wl[k * NCOUT + t];
        out[b * NCOUT + t] = o;
    }
}

extern "C" void kernel_launch(void* const* d_in, const int* in_sizes, int n_in,
                              void* d_out, int out_size, void* d_ws, size_t ws_size,
                              hipStream_t stream)
{
    const float* x    = (const float*)d_in[0];
    const float* adj  = (const float*)d_in[1];
    const float* Wadj = (const float*)d_in[4];
    const float* badj = (const float*)d_in[5];
    const float* W1   = (const float*)d_in[6];
    const float* as1  = (const float*)d_in[7];
    const float* ad1  = (const float*)d_in[8];
    const float* b1   = (const float*)d_in[9];
    const float* W2   = (const float*)d_in[10];
    const float* as2  = (const float*)d_in[11];
    const float* ad2  = (const float*)d_in[12];
    const float* b2   = (const float*)d_in[13];
    const float* lng  = (const float*)d_in[14];
    const float* lnb  = (const float*)d_in[15];
    const float* Wlin = (const float*)d_in[16];
    const float* blin = (const float*)d_in[17];
    float* out = (float*)d_out;

    // workspace layout (bytes):
    char* ws = (char*)d_ws;
    unsigned char* mask = (unsigned char*)ws;            // 40,960,000
    float* hp   = (float*)(ws + 40960000);               // 52,428,800
    float* hbuf = (float*)(ws + 93388800);               // 52,428,800
    float* esrc = (float*)(ws + 145817600);              //  1,638,400
    float* edst = (float*)(ws + 147456000);              //  1,638,400
    short* WtH  = (short*)(ws + 149094400);              //    425,984
    short* WtL  = (short*)(ws + 149520384);              //    425,984  -> end 149,946,368

    hipLaunchKernelGGL(k_wprep, dim3(13, 16), dim3(256), 0, stream, Wadj, WtH, WtL);
    hipLaunchKernelGGL(k_mask,  dim3(4, 4, NB), dim3(256), 0, stream, adj, WtH, WtL, badj, mask);

    // ---- GAT layer 1 (W1) ----
    hipLaunchKernelGGL(k_hp,      dim3(7, NB),        dim3(256), 0, stream, x, W1, hp);
    hipLaunchKernelGGL(k_e,       dim3(NB * NN / 4),  dim3(256), 0, stream, hp, as1, ad1, esrc, edst);
    hipLaunchKernelGGL(k_aggr,    dim3(7, NB),        dim3(128), 0, stream, mask, hp, esrc, edst, b1, hbuf);
    hipLaunchKernelGGL(k_ln_relu, dim3(NB * NN),      dim3(128), 0, stream, hbuf, lng, lnb);

    // ---- GAT layer 2 (W2) ----
    hipLaunchKernelGGL(k_hp,      dim3(7, NB),        dim3(256), 0, stream, hbuf, W2, hp);
    hipLaunchKernelGGL(k_e,       dim3(NB * NN / 4),  dim3(256), 0, stream, hp, as2, ad2, esrc, edst);
    hipLaunchKernelGGL(k_aggr,    dim3(7, NB),        dim3(128), 0, stream, mask, hp, esrc, edst, b2, hbuf);
    hipLaunchKernelGGL(k_ln_relu, dim3(NB * NN),      dim3(128), 0, stream, hbuf, lng, lnb);

    // ---- GAT layer 3 (W2 again, no LN/ReLU) ----
    hipLaunchKernelGGL(k_hp,      dim3(7, NB),        dim3(256), 0, stream, hbuf, W2, hp);
    hipLaunchKernelGGL(k_e,       dim3(NB * NN / 4),  dim3(256), 0, stream, hp, as2, ad2, esrc, edst);
    hipLaunchKernelGGL(k_aggr,    dim3(7, NB),        dim3(128), 0, stream, mask, hp, esrc, edst, b2, hbuf);

    hipLaunchKernelGGL(k_pool_lin, dim3(NB),          dim3(128), 0, stream, hbuf, Wlin, blin, out);
}

// Round 3
// 1111.452 us; speedup vs baseline: 2.8049x; 1.5281x over previous
//
#include <hip/hip_runtime.h>
#include <hip/hip_bf16.h>
#include <math.h>

#define NB 256
#define NN 400
#define NH 128
#define NCOUT 16
#define KP 416   // padded K for Wt (13*32)

static constexpr float LOGIT_THRESH = 0.40546510810816444f; // ln(1.5)
static constexpr float LN_EPS = 1e-5f;

typedef __attribute__((ext_vector_type(8))) short short8v;
typedef __attribute__((ext_vector_type(4))) float f32x4;

static __device__ __forceinline__ short f2bf_rne(float f) {
    unsigned u = __float_as_uint(f);
    unsigned r = (u + 0x7fff + ((u >> 16) & 1)) >> 16;
    return (short)r;
}
static __device__ __forceinline__ float bf2f(short s) {
    return __uint_as_float(((unsigned)(unsigned short)s) << 16);
}

// swizzled LDS offset (in shorts) for 16B chunk c (0..3) of row r in a [R][32]-bf16 tile
static __device__ __forceinline__ int soff(int r, int c) {
    return r * 32 + ((c ^ ((r >> 1) & 3)) << 3);
}
// B-variant: extra (r>>3) XOR so 64B-strided rows spread better on the transpose writes
static __device__ __forceinline__ int soffB(int r, int c) {
    return r * 32 + ((c ^ (((r >> 1) ^ (r >> 3)) & 3)) << 3);
}

// ---------------- Kernel 0: W_adj -> bf16 hi/lo, transposed + padded: Wt[416-pad] ----------------
__global__ __launch_bounds__(256) void k_wprep(const float* __restrict__ W,
                                               short* __restrict__ WtH,
                                               short* __restrict__ WtL)
{
    const int k0 = blockIdx.x * 32, d0 = blockIdx.y * 32;
    __shared__ float tile[32][33];
    const int t = threadIdx.x, cc = t & 31, rr = t >> 5;   // rr 0..7
#pragma unroll
    for (int i = 0; i < 4; ++i) {
        int k = k0 + rr + i * 8, d = d0 + cc;
        tile[rr + i * 8][cc] = (k < NN && d < NN) ? W[k * NN + d] : 0.f;
    }
    __syncthreads();
#pragma unroll
    for (int i = 0; i < 4; ++i) {
        int dr = rr + i * 8;
        int d = d0 + dr, k = k0 + cc;
        float v = tile[cc][dr];
        short h = f2bf_rne(v);
        WtH[d * KP + k] = h;
        WtL[d * KP + k] = f2bf_rne(v - bf2f(h));
    }
}

// ---------------- Kernel 1: mask = (adj@W_adj + b_adj > ln1.5) | (s==d), bf16-split MFMA ----------------
__global__ __launch_bounds__(256) void k_mask(const float* __restrict__ adj,
                                              const short* __restrict__ WtH,
                                              const short* __restrict__ WtL,
                                              const float* __restrict__ badj,
                                              unsigned char* __restrict__ mask)
{
    const int b  = blockIdx.z;
    const int s0 = blockIdx.y * 128;
    const int d0 = blockIdx.x * 128;
    const int t  = threadIdx.x;
    const int lane = t & 63, w = t >> 6;
    const int wm = w >> 1, wn = w & 1;

    __shared__ short Ah[128 * 32], Al[128 * 32], Bh[128 * 32], Bl[128 * 32];

    f32x4 acc[4][4];
#pragma unroll
    for (int i = 0; i < 4; ++i)
#pragma unroll
        for (int j = 0; j < 4; ++j) acc[i][j] = (f32x4){0.f, 0.f, 0.f, 0.f};

    const int sr = t >> 2, sc_ = t & 3;
    const int fc = lane >> 4;
    int aoff[4], boff[4];
#pragma unroll
    for (int i = 0; i < 4; ++i) {
        aoff[i] = soff(wm * 64 + i * 16 + (lane & 15), fc);
        boff[i] = soff(wn * 64 + i * 16 + (lane & 15), fc);
    }

    const float* adjb = adj + (long)b * NN * NN;

    for (int kt = 0; kt < 13; ++kt) {
        const int k0 = kt * 32;
        __syncthreads();
#pragma unroll
        for (int i = 0; i < 2; ++i) {
            const int rr = sr + 64 * i;
            {
                const int s = s0 + rr, kg = k0 + sc_ * 8;
                float x[8];
                if (s < NN && kg < NN) {
                    float4 u0 = *(const float4*)&adjb[(long)s * NN + kg];
                    float4 u1 = *(const float4*)&adjb[(long)s * NN + kg + 4];
                    x[0]=u0.x; x[1]=u0.y; x[2]=u0.z; x[3]=u0.w;
                    x[4]=u1.x; x[5]=u1.y; x[6]=u1.z; x[7]=u1.w;
                } else {
#pragma unroll
                    for (int j = 0; j < 8; ++j) x[j] = 0.f;
                }
                short8v hv, lv;
#pragma unroll
                for (int j = 0; j < 8; ++j) {
                    short h = f2bf_rne(x[j]);
                    hv[j] = h;
                    lv[j] = f2bf_rne(x[j] - bf2f(h));
                }
                *(short8v*)&Ah[soff(rr, sc_)] = hv;
                *(short8v*)&Al[soff(rr, sc_)] = lv;
            }
            {
                const long gi = (long)(d0 + rr) * KP + k0 + sc_ * 8;
                *(short8v*)&Bh[soff(rr, sc_)] = *(const short8v*)&WtH[gi];
                *(short8v*)&Bl[soff(rr, sc_)] = *(const short8v*)&WtL[gi];
            }
        }
        __syncthreads();

        short8v ah[4], al[4], bh[4], bl[4];
#pragma unroll
        for (int i = 0; i < 4; ++i) {
            ah[i] = *(const short8v*)&Ah[aoff[i]];
            al[i] = *(const short8v*)&Al[aoff[i]];
            bh[i] = *(const short8v*)&Bh[boff[i]];
            bl[i] = *(const short8v*)&Bl[boff[i]];
        }
#pragma unroll
        for (int mi = 0; mi < 4; ++mi)
#pragma unroll
            for (int ni = 0; ni < 4; ++ni) {
                acc[mi][ni] = __builtin_amdgcn_mfma_f32_16x16x32_bf16(ah[mi], bh[ni], acc[mi][ni], 0, 0, 0);
                acc[mi][ni] = __builtin_amdgcn_mfma_f32_16x16x32_bf16(al[mi], bh[ni], acc[mi][ni], 0, 0, 0);
                acc[mi][ni] = __builtin_amdgcn_mfma_f32_16x16x32_bf16(ah[mi], bl[ni], acc[mi][ni], 0, 0, 0);
            }
    }

    unsigned char* mb = mask + (long)b * NN * NN;
    const int colb = d0 + wn * 64 + (lane & 15);
    const int rowb = s0 + wm * 64 + ((lane >> 4) << 2);
#pragma unroll
    for (int ni = 0; ni < 4; ++ni) {
        const int d = colb + ni * 16;
        if (d >= NN) continue;
        const float bv = badj[d];
#pragma unroll
        for (int mi = 0; mi < 4; ++mi) {
#pragma unroll
            for (int j = 0; j < 4; ++j) {
                const int s = rowb + mi * 16 + j;
                if (s < NN)
                    mb[(long)s * NN + d] = ((acc[mi][ni][j] + bv) > LOGIT_THRESH || s == d) ? 1 : 0;
            }
        }
    }
}

// ---------------- Kernel 2: hp = h @ W  (per-batch 400x128 @ 128x128, fp32) ----------------
__global__ __launch_bounds__(256) void k_hp(const float* __restrict__ hin,
                                            const float* __restrict__ W,
                                            float* __restrict__ hp)
{
    const int b  = blockIdx.y;
    const int r0 = blockIdx.x * 64;
    const int t  = threadIdx.x;
    const int tx = t & 31, ty = t >> 5;

    __shared__ float as[64][16];
    __shared__ float ws[16][128];

    float acc[8][4] = {};

    const int lkk = t & 15, lr0 = t >> 4;
    const int lc  = t & 127, lkb = t >> 7;

    const float* hb = hin + (long)b * NN * NH;

    for (int k0 = 0; k0 < NH; k0 += 16) {
#pragma unroll
        for (int p = 0; p < 4; ++p) {
            int row = lr0 + p * 16;
            int r = r0 + row;
            as[row][lkk] = (r < NN) ? hb[(long)r * NH + k0 + lkk] : 0.f;
        }
#pragma unroll
        for (int p = 0; p < 8; ++p) {
            int kk = lkb + p * 2;
            ws[kk][lc] = W[(k0 + kk) * NH + lc];
        }
        __syncthreads();
#pragma unroll
        for (int k = 0; k < 16; ++k) {
            float4 bv = *(const float4*)&ws[k][tx * 4];
#pragma unroll
            for (int i = 0; i < 8; ++i) {
                float a = as[ty + 8 * i][k];
                acc[i][0] += a * bv.x; acc[i][1] += a * bv.y;
                acc[i][2] += a * bv.z; acc[i][3] += a * bv.w;
            }
        }
        __syncthreads();
    }

    float* hpb = hp + (long)b * NN * NH;
#pragma unroll
    for (int i = 0; i < 8; ++i) {
        int r = r0 + ty + 8 * i;
        if (r >= NN) continue;
        *(float4*)&hpb[(long)r * NH + tx * 4] =
            make_float4(acc[i][0], acc[i][1], acc[i][2], acc[i][3]);
    }
}

// ---------------- Kernel 2b: e_src/e_dst per row, wave-per-row ----------------
__global__ __launch_bounds__(256) void k_e(const float* __restrict__ hp,
                                           const float* __restrict__ asrc,
                                           const float* __restrict__ adst,
                                           float* __restrict__ esrc,
                                           float* __restrict__ edst)
{
    const int lane = threadIdx.x & 63, wid = threadIdx.x >> 6;
    const long row = (long)blockIdx.x * 4 + wid;
    float v0 = hp[row * NH + lane], v1 = hp[row * NH + 64 + lane];
    float s = v0 * asrc[lane] + v1 * asrc[64 + lane];
    float d = v0 * adst[lane] + v1 * adst[64 + lane];
#pragma unroll
    for (int off = 32; off > 0; off >>= 1) {
        s += __shfl_xor(s, off);
        d += __shfl_xor(d, off);
    }
    if (lane == 0) { esrc[row] = s; edst[row] = d; }
}

// ---------------- Kernel 3: MFMA attention aggregation (one-pass softmax, fused denom) ----------------
// out[d,h] = (sum_s P[s,d]*hp[s,h]) / den[d] + bias[h];  P = mask ? exp(leaky(es[s]+ed[d])) : 0
// Block: 64 dst x 128 feat, 256 threads = 4 waves; K-loop over s in 32-steps, 16x16x32 bf16 MFMA.
__global__ __launch_bounds__(256) void k_aggr(const unsigned char* __restrict__ mask,
                                              const float* __restrict__ hp,
                                              const float* __restrict__ esrc,
                                              const float* __restrict__ edst,
                                              const float* __restrict__ bias,
                                              float* __restrict__ hout)
{
    const int b  = blockIdx.y;
    const int d0 = blockIdx.x * 64;
    const int t  = threadIdx.x;
    const int lane = t & 63, w = t >> 6;

    __shared__ short Pt[64 * 32];     // A tile: rows=d (64), 32 s, soff-swizzled
    __shared__ short Bt[128 * 32];    // B tile: rows=h (128), 32 s, soffB-swizzled
    __shared__ float es_l[416];
    __shared__ float denp[4][64];
    __shared__ float idl[64];

    // load es (padded)
    for (int i = t; i < 416; i += 256) es_l[i] = (i < NN) ? esrc[b * NN + i] : 0.f;

    // P staging mapping: this thread owns dst-row pd, s-chunk pc (=wave id)
    const int pd = t & 63;
    const int pc = t >> 6;
    const bool dvalid = (d0 + pd) < NN;
    const float edv = dvalid ? edst[b * NN + d0 + pd] : 0.f;

    // B staging mapping: h = t&127, rows br..br+15
    const int bh = t & 127;
    const int br = (t >> 7) * 16;

    f32x4 acc[4][2];
#pragma unroll
    for (int mi = 0; mi < 4; ++mi)
#pragma unroll
        for (int ni = 0; ni < 2; ++ni) acc[mi][ni] = (f32x4){0.f, 0.f, 0.f, 0.f};
    float denloc = 0.f;

    const unsigned char* mb = mask + (long)b * NN * NN;
    const float* hpb = hp + (long)b * NN * NH;

    // fragment read offsets
    const int fc = lane >> 4;
    int aoff[4], boff[2];
#pragma unroll
    for (int mi = 0; mi < 4; ++mi) aoff[mi] = soff(mi * 16 + (lane & 15), fc);
#pragma unroll
    for (int ni = 0; ni < 2; ++ni) boff[ni] = soffB(w * 32 + ni * 16 + (lane & 15), fc);

    __syncthreads();   // es_l ready

    for (int kt = 0; kt < 13; ++kt) {
        const int s0 = kt * 32;
        // ---- stage A (= P^T tile), accumulate denominator ----
        {
            const int sb = s0 + pc * 8;
            short8v pv;
#pragma unroll
            for (int j = 0; j < 8; ++j) {
                const int s = sb + j;
                float sc = es_l[s] + edv;
                sc = sc > 0.f ? sc : 0.2f * sc;
                bool valid = (s < NN) && dvalid && mb[(long)s * NN + d0 + pd];
                float p = valid ? __expf(sc) : 0.f;
                pv[j] = f2bf_rne(p);
                denloc += p;
            }
            *(short8v*)&Pt[soff(pd, pc)] = pv;
        }
        // ---- stage B (= hp tile, transposed to [h][s]) ----
        {
#pragma unroll
            for (int q = 0; q < 8; ++q) {
                const int s1 = br + 2 * q;          // local s, even
                const int sg = s0 + s1;
                float v0 = (sg < NN)     ? hpb[(long)sg * NH + bh]       : 0.f;
                float v1 = (sg + 1 < NN) ? hpb[(long)(sg + 1) * NH + bh] : 0.f;
                unsigned pk = ((unsigned)(unsigned short)f2bf_rne(v0)) |
                              (((unsigned)(unsigned short)f2bf_rne(v1)) << 16);
                *(unsigned*)&Bt[soffB(bh, s1 >> 3) + (s1 & 7)] = pk;
            }
        }
        __syncthreads();
        // ---- MFMA ----
        short8v af[4], bf_[2];
#pragma unroll
        for (int mi = 0; mi < 4; ++mi) af[mi] = *(const short8v*)&Pt[aoff[mi]];
#pragma unroll
        for (int ni = 0; ni < 2; ++ni) bf_[ni] = *(const short8v*)&Bt[boff[ni]];
#pragma unroll
        for (int mi = 0; mi < 4; ++mi)
#pragma unroll
            for (int ni = 0; ni < 2; ++ni)
                acc[mi][ni] = __builtin_amdgcn_mfma_f32_16x16x32_bf16(af[mi], bf_[ni], acc[mi][ni], 0, 0, 0);
        __syncthreads();
    }

    denp[pc][pd] = denloc;
    __syncthreads();
    if (t < 64) {
        float den = denp[0][t] + denp[1][t] + denp[2][t] + denp[3][t];
        idl[t] = 1.f / den;
    }
    __syncthreads();

    // epilogue: C layout col = lane&15 (h), row = (lane>>4)*4 + j (d)
    float* hb = hout + (long)b * NN * NH;
    const int hcol = w * 32 + (lane & 15);
    const int drow = (lane >> 4) * 4;
#pragma unroll
    for (int ni = 0; ni < 2; ++ni) {
        const int h = hcol + ni * 16;
        const float bv = bias[h];
#pragma unroll
        for (int mi = 0; mi < 4; ++mi) {
#pragma unroll
            for (int j = 0; j < 4; ++j) {
                const int dl = mi * 16 + drow + j;
                const int d = d0 + dl;
                if (d < NN)
                    hb[(long)d * NH + h] = acc[mi][ni][j] * idl[dl] + bv;
            }
        }
    }
}

// ---------------- Kernel 4: in-place LayerNorm(H) + ReLU ----------------
__global__ __launch_bounds__(128) void k_ln_relu(float* __restrict__ h,
                                                 const float* __restrict__ g,
                                                 const float* __restrict__ bb)
{
    const long row = blockIdx.x;
    const int t = threadIdx.x;
    float x = h[row * NH + t];
    __shared__ float red[128];
    red[t] = x;
    __syncthreads();
    for (int off = 64; off > 0; off >>= 1) { if (t < off) red[t] += red[t + off]; __syncthreads(); }
    float mean = red[0] * (1.f / NH);
    __syncthreads();
    float xm = x - mean;
    red[t] = xm * xm;
    __syncthreads();
    for (int off = 64; off > 0; off >>= 1) { if (t < off) red[t] += red[t + off]; __syncthreads(); }
    float var = red[0] * (1.f / NH);
    float y = xm * rsqrtf(var + LN_EPS) * g[t] + bb[t];
    h[row * NH + t] = fmaxf(y, 0.f);
}

// ---------------- Kernel 5: mean-pool over N + final linear ----------------
__global__ __launch_bounds__(128) void k_pool_lin(const float* __restrict__ h,
                                                  const float* __restrict__ Wl,
                                                  const float* __restrict__ bl,
                                                  float* __restrict__ out)
{
    const int b = blockIdx.x;
    const int t = threadIdx.x;
    const float* hb = h + (long)b * NN * NH;
    float s = 0.f;
    for (int n = 0; n < NN; ++n) s += hb[(long)n * NH + t];
    __shared__ float gl[128];
    gl[t] = s * (1.f / NN);
    __syncthreads();
    if (t < NCOUT) {
        float o = bl[t];
        for (int k = 0; k < NH; ++k) o += gl[k] * Wl[k * NCOUT + t];
        out[b * NCOUT + t] = o;
    }
}

extern "C" void kernel_launch(void* const* d_in, const int* in_sizes, int n_in,
                              void* d_out, int out_size, void* d_ws, size_t ws_size,
                              hipStream_t stream)
{
    const float* x    = (const float*)d_in[0];
    const float* adj  = (const float*)d_in[1];
    const float* Wadj = (const float*)d_in[4];
    const float* badj = (const float*)d_in[5];
    const float* W1   = (const float*)d_in[6];
    const float* as1  = (const float*)d_in[7];
    const float* ad1  = (const float*)d_in[8];
    const float* b1   = (const float*)d_in[9];
    const float* W2   = (const float*)d_in[10];
    const float* as2  = (const float*)d_in[11];
    const float* ad2  = (const float*)d_in[12];
    const float* b2   = (const float*)d_in[13];
    const float* lng  = (const float*)d_in[14];
    const float* lnb  = (const float*)d_in[15];
    const float* Wlin = (const float*)d_in[16];
    const float* blin = (const float*)d_in[17];
    float* out = (float*)d_out;

    char* ws = (char*)d_ws;
    unsigned char* mask = (unsigned char*)ws;            // 40,960,000
    float* hp   = (float*)(ws + 40960000);               // 52,428,800
    float* hbuf = (float*)(ws + 93388800);               // 52,428,800
    float* esrc = (float*)(ws + 145817600);              //  1,638,400
    float* edst = (float*)(ws + 147456000);              //  1,638,400
    short* WtH  = (short*)(ws + 149094400);              //    425,984
    short* WtL  = (short*)(ws + 149520384);              //    425,984

    hipLaunchKernelGGL(k_wprep, dim3(13, 16), dim3(256), 0, stream, Wadj, WtH, WtL);
    hipLaunchKernelGGL(k_mask,  dim3(4, 4, NB), dim3(256), 0, stream, adj, WtH, WtL, badj, mask);

    // ---- GAT layer 1 (W1) ----
    hipLaunchKernelGGL(k_hp,      dim3(7, NB),        dim3(256), 0, stream, x, W1, hp);
    hipLaunchKernelGGL(k_e,       dim3(NB * NN / 4),  dim3(256), 0, stream, hp, as1, ad1, esrc, edst);
    hipLaunchKernelGGL(k_aggr,    dim3(7, NB),        dim3(256), 0, stream, mask, hp, esrc, edst, b1, hbuf);
    hipLaunchKernelGGL(k_ln_relu, dim3(NB * NN),      dim3(128), 0, stream, hbuf, lng, lnb);

    // ---- GAT layer 2 (W2) ----
    hipLaunchKernelGGL(k_hp,      dim3(7, NB),        dim3(256), 0, stream, hbuf, W2, hp);
    hipLaunchKernelGGL(k_e,       dim3(NB * NN / 4),  dim3(256), 0, stream, hp, as2, ad2, esrc, edst);
    hipLaunchKernelGGL(k_aggr,    dim3(7, NB),        dim3(256), 0, stream, mask, hp, esrc, edst, b2, hbuf);
    hipLaunchKernelGGL(k_ln_relu, dim3(NB * NN),      dim3(128), 0, stream, hbuf, lng, lnb);

    // ---- GAT layer 3 (W2 again, no LN/ReLU) ----
    hipLaunchKernelGGL(k_hp,      dim3(7, NB),        dim3(256), 0, stream, hbuf, W2, hp);
    hipLaunchKernelGGL(k_e,       dim3(NB * NN / 4),  dim3(256), 0, stream, hp, as2, ad2, esrc, edst);
    hipLaunchKernelGGL(k_aggr,    dim3(7, NB),        dim3(256), 0, stream, mask, hp, esrc, edst, b2, hbuf);

    hipLaunchKernelGGL(k_pool_lin, dim3(NB),          dim3(128), 0, stream, hbuf, Wlin, blin, out);
}

// Round 4
// 798.057 us; speedup vs baseline: 3.9064x; 1.3927x over previous
//
#include <hip/hip_runtime.h>
#include <hip/hip_bf16.h>
#include <math.h>

#define NB 256
#define NN 400
#define NH 128
#define NCOUT 16
#define NNP 416   // padded N (13*32)
#define DP  512   // padded dst rows for maskT
#define KP  416   // padded K for W_adj prep

static constexpr float LOGIT_THRESH = 0.40546510810816444f; // ln(1.5)
static constexpr float LN_EPS = 1e-5f;

typedef __attribute__((ext_vector_type(8))) short short8v;
typedef __attribute__((ext_vector_type(4))) float f32x4;

static __device__ __forceinline__ short f2bf_rne(float f) {
    unsigned u = __float_as_uint(f);
    unsigned r = (u + 0x7fff + ((u >> 16) & 1)) >> 16;
    return (short)r;
}
static __device__ __forceinline__ float bf2f(short s) {
    return __uint_as_float(((unsigned)(unsigned short)s) << 16);
}

// swizzled LDS offset (in shorts) for 16B chunk c (0..3) of row r in a [R][32]-bf16 tile
static __device__ __forceinline__ int soff(int r, int c) {
    return r * 32 + ((c ^ ((r >> 1) & 3)) << 3);
}

// ---------------- W_adj -> bf16 hi/lo, transposed + padded ----------------
__global__ __launch_bounds__(256) void k_wprep(const float* __restrict__ W,
                                               short* __restrict__ WtH,
                                               short* __restrict__ WtL)
{
    const int k0 = blockIdx.x * 32, d0 = blockIdx.y * 32;
    __shared__ float tile[32][33];
    const int t = threadIdx.x, cc = t & 31, rr = t >> 5;
#pragma unroll
    for (int i = 0; i < 4; ++i) {
        int k = k0 + rr + i * 8, d = d0 + cc;
        tile[rr + i * 8][cc] = (k < NN && d < NN) ? W[k * NN + d] : 0.f;
    }
    __syncthreads();
#pragma unroll
    for (int i = 0; i < 4; ++i) {
        int dr = rr + i * 8;
        int d = d0 + dr, k = k0 + cc;
        float v = tile[cc][dr];
        short h = f2bf_rne(v);
        WtH[d * KP + k] = h;
        WtL[d * KP + k] = f2bf_rne(v - bf2f(h));
    }
}

// ---------------- W (128x128) -> bf16 hi/lo transposed: WT[h][k] ----------------
__global__ __launch_bounds__(256) void k_wprepW(const float* __restrict__ W,
                                                short* __restrict__ WTH,
                                                short* __restrict__ WTL)
{
    const int t = blockIdx.x * 256 + threadIdx.x;   // 16384
    const int h = t >> 7, k = t & 127;
    float v = W[k * NH + h];
    short hi = f2bf_rne(v);
    WTH[h * NH + k] = hi;
    WTL[h * NH + k] = f2bf_rne(v - bf2f(hi));
}

// ---------------- mask GEMM -> maskT[b][d][s] (d-major, padded) ----------------
__global__ __launch_bounds__(256) void k_mask(const float* __restrict__ adj,
                                              const short* __restrict__ WtH,
                                              const short* __restrict__ WtL,
                                              const float* __restrict__ badj,
                                              unsigned char* __restrict__ maskT)
{
    const int b  = blockIdx.z;
    const int s0 = blockIdx.y * 128;
    const int d0 = blockIdx.x * 128;
    const int t  = threadIdx.x;
    const int lane = t & 63, w = t >> 6;
    const int wm = w >> 1, wn = w & 1;

    __shared__ short Ah[128 * 32], Al[128 * 32], Bh[128 * 32], Bl[128 * 32];

    f32x4 acc[4][4];
#pragma unroll
    for (int i = 0; i < 4; ++i)
#pragma unroll
        for (int j = 0; j < 4; ++j) acc[i][j] = (f32x4){0.f, 0.f, 0.f, 0.f};

    const int sr = t >> 2, sc_ = t & 3;
    const int fc = lane >> 4;
    int aoff[4], boff[4];
#pragma unroll
    for (int i = 0; i < 4; ++i) {
        aoff[i] = soff(wm * 64 + i * 16 + (lane & 15), fc);
        boff[i] = soff(wn * 64 + i * 16 + (lane & 15), fc);
    }

    const float* adjb = adj + (long)b * NN * NN;

    for (int kt = 0; kt < 13; ++kt) {
        const int k0 = kt * 32;
        __syncthreads();
#pragma unroll
        for (int i = 0; i < 2; ++i) {
            const int rr = sr + 64 * i;
            {
                const int s = s0 + rr, kg = k0 + sc_ * 8;
                float x[8];
                if (s < NN && kg < NN) {
                    float4 u0 = *(const float4*)&adjb[(long)s * NN + kg];
                    float4 u1 = *(const float4*)&adjb[(long)s * NN + kg + 4];
                    x[0]=u0.x; x[1]=u0.y; x[2]=u0.z; x[3]=u0.w;
                    x[4]=u1.x; x[5]=u1.y; x[6]=u1.z; x[7]=u1.w;
                } else {
#pragma unroll
                    for (int j = 0; j < 8; ++j) x[j] = 0.f;
                }
                short8v hv, lv;
#pragma unroll
                for (int j = 0; j < 8; ++j) {
                    short h = f2bf_rne(x[j]);
                    hv[j] = h;
                    lv[j] = f2bf_rne(x[j] - bf2f(h));
                }
                *(short8v*)&Ah[soff(rr, sc_)] = hv;
                *(short8v*)&Al[soff(rr, sc_)] = lv;
            }
            {
                const long gi = (long)(d0 + rr) * KP + k0 + sc_ * 8;
                *(short8v*)&Bh[soff(rr, sc_)] = *(const short8v*)&WtH[gi];
                *(short8v*)&Bl[soff(rr, sc_)] = *(const short8v*)&WtL[gi];
            }
        }
        __syncthreads();

        short8v ah[4], al[4], bh[4], bl[4];
#pragma unroll
        for (int i = 0; i < 4; ++i) {
            ah[i] = *(const short8v*)&Ah[aoff[i]];
            al[i] = *(const short8v*)&Al[aoff[i]];
            bh[i] = *(const short8v*)&Bh[boff[i]];
            bl[i] = *(const short8v*)&Bl[boff[i]];
        }
#pragma unroll
        for (int mi = 0; mi < 4; ++mi)
#pragma unroll
            for (int ni = 0; ni < 4; ++ni) {
                acc[mi][ni] = __builtin_amdgcn_mfma_f32_16x16x32_bf16(ah[mi], bh[ni], acc[mi][ni], 0, 0, 0);
                acc[mi][ni] = __builtin_amdgcn_mfma_f32_16x16x32_bf16(al[mi], bh[ni], acc[mi][ni], 0, 0, 0);
                acc[mi][ni] = __builtin_amdgcn_mfma_f32_16x16x32_bf16(ah[mi], bl[ni], acc[mi][ni], 0, 0, 0);
            }
    }

    // epilogue -> maskT[d][s] packed uchar4 (s groups of 4, never straddle 416)
    unsigned char* mTb = maskT + (long)b * DP * NNP;
    const int colb = d0 + wn * 64 + (lane & 15);            // d
    const int rowb = s0 + wm * 64 + ((lane >> 4) << 2);     // s base
#pragma unroll
    for (int ni = 0; ni < 4; ++ni) {
        const int d = colb + ni * 16;
        if (d >= NN) continue;
        const float bv = badj[d];
#pragma unroll
        for (int mi = 0; mi < 4; ++mi) {
            const int sg = rowb + mi * 16;
            if (sg >= NNP) continue;
            uchar4 pk;
#pragma unroll
            for (int j = 0; j < 4; ++j) {
                const int s = sg + j;
                bool v = (s < NN) && ((acc[mi][ni][j] + bv) > LOGIT_THRESH || s == d);
                ((unsigned char*)&pk)[j] = v ? 1 : 0;
            }
            *(uchar4*)&mTb[(long)d * NNP + sg] = pk;
        }
    }
}

// ---------------- hpT = (hin @ W)^T as bf16, hi/lo-split MFMA, no barriers ----------------
// C rows = h (A = W^T, pre-split), C cols = s (B = hin rows, split in-register)
__global__ __launch_bounds__(256) void k_hp(const float* __restrict__ hin,
                                            const short* __restrict__ WTH,
                                            const short* __restrict__ WTL,
                                            short* __restrict__ hpT)
{
    const int b  = blockIdx.y;
    const int s0 = blockIdx.x * 128;
    const int t  = threadIdx.x;
    const int lane = t & 63, w = t >> 6;
    const int wm = w >> 1, wn = w & 1;   // wm: h-half, wn: s-half
    const int fr = lane & 15, fc = lane >> 4;

    const float* hb = hin + (long)b * NN * NH;
    short* hpTb = hpT + (long)b * NH * NNP;

    f32x4 acc[4][4];
#pragma unroll
    for (int m = 0; m < 4; ++m)
#pragma unroll
        for (int n = 0; n < 4; ++n) acc[m][n] = (f32x4){0.f, 0.f, 0.f, 0.f};

    for (int kt = 0; kt < 4; ++kt) {
        const int k0 = kt * 32;
        short8v ah[4], al[4], bh[4], bl[4];
#pragma unroll
        for (int m = 0; m < 4; ++m) {
            const int h = wm * 64 + m * 16 + fr;
            ah[m] = *(const short8v*)&WTH[h * NH + k0 + fc * 8];
            al[m] = *(const short8v*)&WTL[h * NH + k0 + fc * 8];
        }
#pragma unroll
        for (int n = 0; n < 4; ++n) {
            const int s = s0 + wn * 64 + n * 16 + fr;
            float x[8];
            if (s < NN) {
                float4 u0 = *(const float4*)&hb[(long)s * NH + k0 + fc * 8];
                float4 u1 = *(const float4*)&hb[(long)s * NH + k0 + fc * 8 + 4];
                x[0]=u0.x; x[1]=u0.y; x[2]=u0.z; x[3]=u0.w;
                x[4]=u1.x; x[5]=u1.y; x[6]=u1.z; x[7]=u1.w;
            } else {
#pragma unroll
                for (int j = 0; j < 8; ++j) x[j] = 0.f;
            }
#pragma unroll
            for (int j = 0; j < 8; ++j) {
                short hi = f2bf_rne(x[j]);
                bh[n][j] = hi;
                bl[n][j] = f2bf_rne(x[j] - bf2f(hi));
            }
        }
#pragma unroll
        for (int m = 0; m < 4; ++m)
#pragma unroll
            for (int n = 0; n < 4; ++n) {
                acc[m][n] = __builtin_amdgcn_mfma_f32_16x16x32_bf16(ah[m], bh[n], acc[m][n], 0, 0, 0);
                acc[m][n] = __builtin_amdgcn_mfma_f32_16x16x32_bf16(al[m], bh[n], acc[m][n], 0, 0, 0);
                acc[m][n] = __builtin_amdgcn_mfma_f32_16x16x32_bf16(ah[m], bl[n], acc[m][n], 0, 0, 0);
            }
    }

    // store: row = h (fc*4+j), col = s (fr); pads (s in [400,416)) get 0 naturally
#pragma unroll
    for (int m = 0; m < 4; ++m) {
#pragma unroll
        for (int n = 0; n < 4; ++n) {
            const int s = s0 + wn * 64 + n * 16 + fr;
            if (s >= NNP) continue;
#pragma unroll
            for (int j = 0; j < 4; ++j) {
                const int h = wm * 64 + m * 16 + fc * 4 + j;
                hpTb[h * NNP + s] = f2bf_rne(acc[m][n][j]);
            }
        }
    }
}

// ---------------- per-row score pieces: es, ed and exp tables ----------------
__global__ __launch_bounds__(256) void k_e(const short* __restrict__ hpT,
                                           const float* __restrict__ asrc,
                                           const float* __restrict__ adst,
                                           float* __restrict__ esA, float* __restrict__ edA,
                                           float* __restrict__ e1sA, float* __restrict__ e2sA,
                                           float* __restrict__ e1dA, float* __restrict__ e2dA)
{
    const int b = blockIdx.x;
    const int t = threadIdx.x;
    const short* hb = hpT + (long)b * NH * NNP;
    const bool has2 = (t + 256) < NNP;
    float es0 = 0.f, ed0 = 0.f, es1 = 0.f, ed1 = 0.f;
    for (int h = 0; h < NH; ++h) {
        float av = asrc[h], dv = adst[h];
        float v0 = bf2f(hb[h * NNP + t]);
        es0 += v0 * av; ed0 += v0 * dv;
        if (has2) {
            float v1 = bf2f(hb[h * NNP + t + 256]);
            es1 += v1 * av; ed1 += v1 * dv;
        }
    }
    long o = (long)b * NNP + t;
    esA[o] = es0; edA[o] = ed0;
    e1sA[o] = __expf(es0); e2sA[o] = __expf(0.2f * es0);
    e1dA[o] = __expf(ed0); e2dA[o] = __expf(0.2f * ed0);
    if (has2) {
        o += 256;
        esA[o] = es1; edA[o] = ed1;
        e1sA[o] = __expf(es1); e2sA[o] = __expf(0.2f * es1);
        e1dA[o] = __expf(ed1); e2dA[o] = __expf(0.2f * ed1);
    }
}

// ---------------- fragment-direct MFMA aggregation, exp-free P, fused denom ----------------
// out[d,h] = (sum_s P[d,s]*hpT[h,s]) / den[d] + bias[h]
// 128 dst x 128 feat per block, 4 waves (wm: d-half, wn: h-half), no barriers in k-loop.
__global__ __launch_bounds__(256) void k_aggr(const unsigned char* __restrict__ maskT,
                                              const short* __restrict__ hpT,
                                              const float* __restrict__ esA,
                                              const float* __restrict__ edA,
                                              const float* __restrict__ e1sA,
                                              const float* __restrict__ e2sA,
                                              const float* __restrict__ e1dA,
                                              const float* __restrict__ e2dA,
                                              const float* __restrict__ bias,
                                              float* __restrict__ hout)
{
    const int b  = blockIdx.y;
    const int d0 = blockIdx.x * 128;
    const int t  = threadIdx.x;
    const int lane = t & 63, w = t >> 6;
    const int wm = w >> 1, wn = w & 1;
    const int fr = lane & 15, fc = lane >> 4;

    __shared__ float es_l[NNP], e1s_l[NNP], e2s_l[NNP];
    __shared__ float den_l[128];

    for (int i = t; i < NNP; i += 256) {
        const long o = (long)b * NNP + i;
        es_l[i]  = esA[o];
        e1s_l[i] = e1sA[o];
        e2s_l[i] = e2sA[o];
    }

    float edv[4], e1dv[4], e2dv[4];
#pragma unroll
    for (int m = 0; m < 4; ++m) {
        const int d = d0 + wm * 64 + m * 16 + fr;
        const bool v = d < NN;
        const long o = (long)b * NNP + d;
        edv[m]  = v ? edA[o]  : 0.f;
        e1dv[m] = v ? e1dA[o] : 0.f;
        e2dv[m] = v ? e2dA[o] : 0.f;
    }
    __syncthreads();

    f32x4 acc[4][4];
#pragma unroll
    for (int m = 0; m < 4; ++m)
#pragma unroll
        for (int n = 0; n < 4; ++n) acc[m][n] = (f32x4){0.f, 0.f, 0.f, 0.f};
    float den[4] = {0.f, 0.f, 0.f, 0.f};

    const unsigned char* mTb = maskT + (long)b * DP * NNP;
    const short* hTb = hpT + (long)b * NH * NNP;

    for (int kt = 0; kt < 13; ++kt) {
        const int sb = kt * 32 + fc * 8;
        // B fragments: direct b128 from hpT
        short8v bf_[4];
#pragma unroll
        for (int n = 0; n < 4; ++n) {
            const int h = wn * 64 + n * 16 + fr;
            bf_[n] = *(const short8v*)&hTb[h * NNP + sb];
        }
        // s-shared values (LDS broadcast)
        float es8[8], e18[8], e28[8];
#pragma unroll
        for (int j = 0; j < 8; ++j) {
            es8[j] = es_l[sb + j];
            e18[j] = e1s_l[sb + j];
            e28[j] = e2s_l[sb + j];
        }
        // A fragments: build P in-register
#pragma unroll
        for (int m = 0; m < 4; ++m) {
            const int d = d0 + wm * 64 + m * 16 + fr;
            const unsigned long long mk = *(const unsigned long long*)&mTb[(long)d * NNP + sb];
            short8v pv;
#pragma unroll
            for (int j = 0; j < 8; ++j) {
                const float sc = es8[j] + edv[m];
                float p = sc > 0.f ? e18[j] * e1dv[m] : e28[j] * e2dv[m];
                p = ((mk >> (8 * j)) & 0xffULL) ? p : 0.f;
                den[m] += p;
                pv[j] = f2bf_rne(p);
            }
#pragma unroll
            for (int n = 0; n < 4; ++n)
                acc[m][n] = __builtin_amdgcn_mfma_f32_16x16x32_bf16(pv, bf_[n], acc[m][n], 0, 0, 0);
        }
    }

    // denominator: reduce across the 4 k-groups (lanes fr, fr+16, fr+32, fr+48)
#pragma unroll
    for (int m = 0; m < 4; ++m) {
        den[m] += __shfl_xor(den[m], 16);
        den[m] += __shfl_xor(den[m], 32);
    }
    if (wn == 0 && fc == 0) {
#pragma unroll
        for (int m = 0; m < 4; ++m) den_l[wm * 64 + m * 16 + fr] = den[m];
    }
    __syncthreads();

    float bvh[4];
#pragma unroll
    for (int n = 0; n < 4; ++n) bvh[n] = bias[wn * 64 + n * 16 + fr];

    float* hb = hout + (long)b * NN * NH;
#pragma unroll
    for (int m = 0; m < 4; ++m) {
#pragma unroll
        for (int j = 0; j < 4; ++j) {
            const int dl = wm * 64 + m * 16 + fc * 4 + j;
            const int d = d0 + dl;
            if (d >= NN) continue;
            const float idn = 1.f / den_l[dl];
#pragma unroll
            for (int n = 0; n < 4; ++n) {
                const int h = wn * 64 + n * 16 + fr;
                hb[(long)d * NH + h] = acc[m][n][j] * idn + bvh[n];
            }
        }
    }
}

// ---------------- in-place LayerNorm(H) + ReLU ----------------
__global__ __launch_bounds__(128) void k_ln_relu(float* __restrict__ h,
                                                 const float* __restrict__ g,
                                                 const float* __restrict__ bb)
{
    const long row = blockIdx.x;
    const int t = threadIdx.x;
    float x = h[row * NH + t];
    __shared__ float red[128];
    red[t] = x;
    __syncthreads();
    for (int off = 64; off > 0; off >>= 1) { if (t < off) red[t] += red[t + off]; __syncthreads(); }
    float mean = red[0] * (1.f / NH);
    __syncthreads();
    float xm = x - mean;
    red[t] = xm * xm;
    __syncthreads();
    for (int off = 64; off > 0; off >>= 1) { if (t < off) red[t] += red[t + off]; __syncthreads(); }
    float var = red[0] * (1.f / NH);
    float y = xm * rsqrtf(var + LN_EPS) * g[t] + bb[t];
    h[row * NH + t] = fmaxf(y, 0.f);
}

// ---------------- mean-pool over N + final linear ----------------
__global__ __launch_bounds__(128) void k_pool_lin(const float* __restrict__ h,
                                                  const float* __restrict__ Wl,
                                                  const float* __restrict__ bl,
                                                  float* __restrict__ out)
{
    const int b = blockIdx.x;
    const int t = threadIdx.x;
    const float* hb = h + (long)b * NN * NH;
    float s = 0.f;
    for (int n = 0; n < NN; ++n) s += hb[(long)n * NH + t];
    __shared__ float gl[128];
    gl[t] = s * (1.f / NN);
    __syncthreads();
    if (t < NCOUT) {
        float o = bl[t];
        for (int k = 0; k < NH; ++k) o += gl[k] * Wl[k * NCOUT + t];
        out[b * NCOUT + t] = o;
    }
}

extern "C" void kernel_launch(void* const* d_in, const int* in_sizes, int n_in,
                              void* d_out, int out_size, void* d_ws, size_t ws_size,
                              hipStream_t stream)
{
    const float* x    = (const float*)d_in[0];
    const float* adj  = (const float*)d_in[1];
    const float* Wadj = (const float*)d_in[4];
    const float* badj = (const float*)d_in[5];
    const float* W1   = (const float*)d_in[6];
    const float* as1  = (const float*)d_in[7];
    const float* ad1  = (const float*)d_in[8];
    const float* b1   = (const float*)d_in[9];
    const float* W2   = (const float*)d_in[10];
    const float* as2  = (const float*)d_in[11];
    const float* ad2  = (const float*)d_in[12];
    const float* b2   = (const float*)d_in[13];
    const float* lng  = (const float*)d_in[14];
    const float* lnb  = (const float*)d_in[15];
    const float* Wlin = (const float*)d_in[16];
    const float* blin = (const float*)d_in[17];
    float* out = (float*)d_out;

    // workspace layout (bytes):
    char* ws = (char*)d_ws;
    unsigned char* maskT = (unsigned char*)ws;        // 256*512*416      = 54,525,952
    short* hpT  = (short*)(ws + 54525952);            // 256*128*416*2    = 27,262,976
    float* hbuf = (float*)(ws + 81788928);            // 256*400*128*4    = 52,428,800
    float* esA  = (float*)(ws + 134217728);           // 6 x 256*416*4
    float* edA  = (float*)(ws + 134643712);
    float* e1sA = (float*)(ws + 135069696);
    float* e2sA = (float*)(ws + 135495680);
    float* e1dA = (float*)(ws + 135921664);
    float* e2dA = (float*)(ws + 136347648);
    short* WtH  = (short*)(ws + 136773632);           // 425,984
    short* WtL  = (short*)(ws + 137199616);           // 425,984
    short* WT1H = (short*)(ws + 137625600);           // 32,768 each
    short* WT1L = (short*)(ws + 137658368);
    short* WT2H = (short*)(ws + 137691136);
    short* WT2L = (short*)(ws + 137723904);           // end 137,756,672

    hipLaunchKernelGGL(k_wprep,  dim3(13, 16), dim3(256), 0, stream, Wadj, WtH, WtL);
    hipLaunchKernelGGL(k_wprepW, dim3(64),     dim3(256), 0, stream, W1, WT1H, WT1L);
    hipLaunchKernelGGL(k_wprepW, dim3(64),     dim3(256), 0, stream, W2, WT2H, WT2L);
    hipLaunchKernelGGL(k_mask,   dim3(4, 4, NB), dim3(256), 0, stream, adj, WtH, WtL, badj, maskT);

    // ---- GAT layer 1 ----
    hipLaunchKernelGGL(k_hp,      dim3(4, NB),   dim3(256), 0, stream, x, WT1H, WT1L, hpT);
    hipLaunchKernelGGL(k_e,       dim3(NB),      dim3(256), 0, stream, hpT, as1, ad1, esA, edA, e1sA, e2sA, e1dA, e2dA);
    hipLaunchKernelGGL(k_aggr,    dim3(4, NB),   dim3(256), 0, stream, maskT, hpT, esA, edA, e1sA, e2sA, e1dA, e2dA, b1, hbuf);
    hipLaunchKernelGGL(k_ln_relu, dim3(NB * NN), dim3(128), 0, stream, hbuf, lng, lnb);

    // ---- GAT layer 2 ----
    hipLaunchKernelGGL(k_hp,      dim3(4, NB),   dim3(256), 0, stream, hbuf, WT2H, WT2L, hpT);
    hipLaunchKernelGGL(k_e,       dim3(NB),      dim3(256), 0, stream, hpT, as2, ad2, esA, edA, e1sA, e2sA, e1dA, e2dA);
    hipLaunchKernelGGL(k_aggr,    dim3(4, NB),   dim3(256), 0, stream, maskT, hpT, esA, edA, e1sA, e2sA, e1dA, e2dA, b2, hbuf);
    hipLaunchKernelGGL(k_ln_relu, dim3(NB * NN), dim3(128), 0, stream, hbuf, lng, lnb);

    // ---- GAT layer 3 (W2 again, no LN/ReLU) ----
    hipLaunchKernelGGL(k_hp,      dim3(4, NB),   dim3(256), 0, stream, hbuf, WT2H, WT2L, hpT);
    hipLaunchKernelGGL(k_e,       dim3(NB),      dim3(256), 0, stream, hpT, as2, ad2, esA, edA, e1sA, e2sA, e1dA, e2dA);
    hipLaunchKernelGGL(k_aggr,    dim3(4, NB),   dim3(256), 0, stream, maskT, hpT, esA, edA, e1sA, e2sA, e1dA, e2dA, b2, hbuf);

    hipLaunchKernelGGL(k_pool_lin, dim3(NB),     dim3(128), 0, stream, hbuf, Wlin, blin, out);
}